// Round 2
// baseline (1572.103 us; speedup 1.0000x reference)
//
#include <hip/hip_runtime.h>
#include <hip/hip_bf16.h>

// Problem constants
constexpr int BATCH = 8192;   // M
constexpr int THEADS = 137;   // number of predict heads
constexpr int DFEA = 384;     // reduction dim of GEMM1
constexpr int KHID = 128;     // per-head hidden width
constexpr float EPS_BN = 1e-5f;
constexpr float SLOPE = 0.01f;

constexpr size_t N_F  = (size_t)BATCH * DFEA;          // 3,145,728
constexpr size_t N_W1 = (size_t)THEADS * KHID * DFEA;  // 6,733,824
constexpr size_t WS_NEED = (N_F + N_W1) * sizeof(__hip_bfloat16);
constexpr int C_F8 = (int)(N_F / 8);                   // 393,216
constexpr int C_T8 = (int)((N_F + N_W1) / 8);          // 1,234,944

constexpr int GRP   = 8;                               // M-groups per head
constexpr int MB    = BATCH / GRP;                     // 1024 rows per block
constexpr int NBLK3 = THEADS * GRP;                    // 1096 blocks

typedef __attribute__((ext_vector_type(8))) short bf16x8;   // 8 bf16 = 4 VGPRs
typedef __attribute__((ext_vector_type(4))) float f32x4;

__device__ __forceinline__ short cvt_bf16(float x) {
    __hip_bfloat16 b = __float2bfloat16(x);
    return *(short*)&b;
}

__device__ __forceinline__ bf16x8 load8_cvt(const float* __restrict__ g) {
    f32x4 lo = *(const f32x4*)g;
    f32x4 hi = *(const f32x4*)(g + 4);
    bf16x8 r;
    r[0] = cvt_bf16(lo[0]); r[1] = cvt_bf16(lo[1]);
    r[2] = cvt_bf16(lo[2]); r[3] = cvt_bf16(lo[3]);
    r[4] = cvt_bf16(hi[0]); r[5] = cvt_bf16(hi[1]);
    r[6] = cvt_bf16(hi[2]); r[7] = cvt_bf16(hi[3]);
    return r;
}

__device__ __forceinline__ void gload16(const void* g, void* s) {
    // async global->LDS, 16B/lane; HW dest = readfirstlane(base) + lane*16
    __builtin_amdgcn_global_load_lds((const __attribute__((address_space(1))) void*)g,
                                     (__attribute__((address_space(3))) void*)s,
                                     16, 0, 0);
}

// ---------------- pre-pass: fp32 -> bf16 bulk convert (f then W1, one launch) ----
__global__ __launch_bounds__(256) void cvt_pass(const float* __restrict__ f,
                                                const float* __restrict__ W1,
                                                __hip_bfloat16* __restrict__ ws) {
    int i = blockIdx.x * 256 + threadIdx.x;
    if (i < C_F8)
        *(bf16x8*)(ws + (size_t)i * 8) = load8_cvt(f + (size_t)i * 8);
    else if (i < C_T8)
        *(bf16x8*)(ws + (size_t)i * 8) = load8_cvt(W1 + ((size_t)i - C_F8) * 8);
}

// 8 B-fragment ds_reads + 8 MFMA for one 16-row A-frag against the full 128-col panel.
// B LDS layout: [128 rows][24 slots of 16B]; slot (r,s) holds kblock (s&~7)|((s&7)^(r&7)).
__device__ __forceinline__ void mfma8(const bf16x8 af,
                                      const __hip_bfloat16* __restrict__ bsrc,
                                      int slotOff, int row16, f32x4 acc[8]) {
    bf16x8 bfr[8];
    #pragma unroll
    for (int bi = 0; bi < 8; ++bi)
        bfr[bi] = *(const bf16x8*)&bsrc[(size_t)((bi * 16 + row16) * 24 + slotOff) * 8];
    __builtin_amdgcn_s_setprio(1);
    #pragma unroll
    for (int bi = 0; bi < 8; ++bi)
        acc[bi] = __builtin_amdgcn_mfma_f32_16x16x32_bf16(af, bfr[bi], acc[bi], 0, 0, 0);
    __builtin_amdgcn_s_setprio(0);
}

// fused epilogue for one 16-row subtile: BN(eval) + LeakyReLU + dot(W2), in-wave reduce
__device__ __forceinline__ void epilogue_store(const f32x4 acc[8],
                                               const float* __restrict__ sc,
                                               const float* __restrict__ cc,
                                               const float* __restrict__ w2v,
                                               float b2t, int baseRow, int quad,
                                               int row16, int t, float* __restrict__ out) {
    float p[4];
    #pragma unroll
    for (int r = 0; r < 4; ++r) {
        float a = 0.f;
        #pragma unroll
        for (int bi = 0; bi < 8; ++bi) {
            float y = acc[bi][r] * sc[bi] + cc[bi];
            y = (y >= 0.f) ? y : SLOPE * y;   // LeakyReLU
            a += y * w2v[bi];
        }
        p[r] = a;
    }
    // reduce across 16 column-lanes (C/D col = lane&15); masks<16 stay in 16-lane group
    #pragma unroll
    for (int mask = 1; mask <= 8; mask <<= 1)
        #pragma unroll
        for (int r = 0; r < 4; ++r)
            p[r] += __shfl_xor(p[r], mask);
    if (row16 == 0) {
        #pragma unroll
        for (int r = 0; r < 4; ++r) {
            const int row = baseRow + quad * 4 + r;
            out[(size_t)row * THEADS + t] = p[r] + b2t;
        }
    }
}

// ---------------- main fused kernel v3: persistent-head, B-resident, 2 barriers -----
// One head x 1024 rows per block. 16 waves (4/SIMD TLP), VGPR<=128 so the full block
// is resident. B panel (128x384 bf16 = 96KB) staged once into LDS in two K-halves:
// counted vmcnt(3) releases half0 early so subtile0's first-half compute overlaps
// half1 staging. After the 2nd barrier the kernel is barrier-free: waves free-run
// over 4x 16-row subtiles, A-frags global->reg with depth-2 prefetch (L2-served:
// bid%8 == m-group == XCD, so each XCD's 786KB f-slice is L2-resident).
__global__ __launch_bounds__(1024, 4) void fused_heads_v3(
    const __hip_bfloat16* __restrict__ fb,     // [8192, 384] bf16
    const __hip_bfloat16* __restrict__ W1b,    // [137*128, 384] bf16
    const float* __restrict__ b1,
    const float* __restrict__ gmm,
    const float* __restrict__ bta,
    const float* __restrict__ rmean,
    const float* __restrict__ rvar,
    const float* __restrict__ W2,
    const float* __restrict__ b2,
    float* __restrict__ out)                   // [8192, 137]
{
    __shared__ __attribute__((aligned(16))) __hip_bfloat16 Bs0[128 * 192]; // K   0..191, 48KB
    __shared__ __attribute__((aligned(16))) __hip_bfloat16 Bs1[128 * 192]; // K 192..383, 48KB

    const int tid   = threadIdx.x;
    const int lane  = tid & 63;
    const int w     = tid >> 6;          // wave 0..15, owns rows w*64..+64
    const int row16 = lane & 15;
    const int quad  = lane >> 4;
    const int xl    = row16 & 7;

    const int bid = blockIdx.x;
    const int t   = bid >> 3;            // head   (GRP == 8)
    const int mg  = bid & 7;             // m-group == XCD under round-robin dispatch
    const int m0  = mg * MB;
    const int n0  = t * KHID;

    // ---- epilogue constants first (their drain happens under staging latency) ----
    float sc[8], cc[8], w2v[8];
    #pragma unroll
    for (int bi = 0; bi < 8; ++bi) {
        const int n = n0 + bi * 16 + row16;
        const float sv = gmm[n] * rsqrtf(rvar[n] + EPS_BN);
        sc[bi]  = sv;
        cc[bi]  = bta[n] + (b1[n] - rmean[n]) * sv;
        w2v[bi] = W2[n];
    }
    const float b2t = b2[t];

    // ---- stage B: half0 (3 gloads/thread) then half1 (3 gloads/thread) -----------
    #pragma unroll
    for (int h = 0; h < 2; ++h)
        #pragma unroll
        for (int i = 0; i < 3; ++i) {
            const int li = tid + i * 1024;           // 16B slot 0..3071 within half
            const int r  = li / 24;                  // B row 0..127
            const int s  = li - r * 24;              // slot-in-row 0..23
            const int kb = h * 24 + ((s & ~7) | ((s & 7) ^ (r & 7)));
            gload16(W1b + (size_t)(n0 + r) * DFEA + kb * 8,
                    (h ? Bs1 : Bs0) + (size_t)li * 8);
        }

    asm volatile("s_waitcnt vmcnt(3)" ::: "memory");  // oldest 3 = half0 complete
    __builtin_amdgcn_s_barrier();                     // half0 valid for all waves
    __builtin_amdgcn_sched_barrier(0);

    const __hip_bfloat16* aBase = fb + (size_t)(m0 + w * 64 + row16) * DFEA + quad * 8;
    const int q2e = quad ^ xl;          // even-kk bank-swizzled slot (low 3 bits)
    const int q2o = q2e ^ 4;            // odd-kk

    // ---- subtile 0 (peeled: mid-K barrier once half1 must be valid) --------------
    {
        f32x4 acc[8];
        #pragma unroll
        for (int bi = 0; bi < 8; ++bi) acc[bi] = (f32x4){0.f, 0.f, 0.f, 0.f};
        bf16x8 a0 = *(const bf16x8*)(aBase);
        bf16x8 a1 = *(const bf16x8*)(aBase + 32);
        #pragma unroll
        for (int ktl = 0; ktl < 12; ++ktl) {
            const bf16x8 af = a0;
            a0 = a1;
            if (ktl < 10) a1 = *(const bf16x8*)(aBase + (ktl + 2) * 32);
            const int kk = ktl % 6;
            mfma8(af, (ktl < 6) ? Bs0 : Bs1,
                  (kk >> 1) * 8 + ((kk & 1) ? q2o : q2e), row16, acc);
            if (ktl == 5) {
                asm volatile("s_waitcnt vmcnt(0)" ::: "memory"); // half1 staged
                __builtin_amdgcn_s_barrier();
                __builtin_amdgcn_sched_barrier(0);
            }
        }
        epilogue_store(acc, sc, cc, w2v, b2t, m0 + w * 64, quad, row16, t, out);
    }

    // ---- subtiles 1..3: fully barrier-free ---------------------------------------
    #pragma unroll 1
    for (int sub = 1; sub < 4; ++sub) {
        const __hip_bfloat16* aR = aBase + (size_t)sub * 16 * DFEA;
        f32x4 acc[8];
        #pragma unroll
        for (int bi = 0; bi < 8; ++bi) acc[bi] = (f32x4){0.f, 0.f, 0.f, 0.f};
        bf16x8 a0 = *(const bf16x8*)(aR);
        bf16x8 a1 = *(const bf16x8*)(aR + 32);
        #pragma unroll
        for (int ktl = 0; ktl < 12; ++ktl) {
            const bf16x8 af = a0;
            a0 = a1;
            if (ktl < 10) a1 = *(const bf16x8*)(aR + (ktl + 2) * 32);
            const int kk = ktl % 6;
            mfma8(af, (ktl < 6) ? Bs0 : Bs1,
                  (kk >> 1) * 8 + ((kk & 1) ? q2o : q2e), row16, acc);
        }
        epilogue_store(acc, sc, cc, w2v, b2t, m0 + w * 64 + sub * 16, quad, row16, t, out);
    }
}

// ---------------- fallback: direct fp32 path (unchanged) ---------------------------
__global__ __launch_bounds__(256) void fused_heads_f32(
    const float* __restrict__ f, const float* __restrict__ W1,
    const float* __restrict__ b1, const float* __restrict__ gmm,
    const float* __restrict__ bta, const float* __restrict__ rmean,
    const float* __restrict__ rvar, const float* __restrict__ W2,
    const float* __restrict__ b2, float* __restrict__ out)
{
    __shared__ __attribute__((aligned(16))) __hip_bfloat16 As[128 * 32];
    __shared__ __attribute__((aligned(16))) __hip_bfloat16 Bs[128 * 32];
    __shared__ float red[2][128];

    const int tid  = threadIdx.x;
    const int lane = tid & 63;
    const int wave = tid >> 6;
    const int wmv = wave >> 1, wn = wave & 1;
    const int m0 = blockIdx.x * 128;
    const int t  = blockIdx.y;
    const int n0 = t * KHID;

    const int li0 = tid, li1 = tid + 256;
    const int r0 = li0 >> 2, c0 = (li0 & 3) * 8;
    const int r1 = li1 >> 2, c1 = (li1 & 3) * 8;
    const float* gA0 = f  + (size_t)(m0 + r0) * DFEA + c0;
    const float* gA1 = f  + (size_t)(m0 + r1) * DFEA + c1;
    const float* gB0 = W1 + (size_t)(n0 + r0) * DFEA + c0;
    const float* gB1 = W1 + (size_t)(n0 + r1) * DFEA + c1;

    const int row16 = lane & 15, quad = lane >> 4;

    f32x4 acc[4][4];
    #pragma unroll
    for (int i = 0; i < 4; ++i)
        #pragma unroll
        for (int jx = 0; jx < 4; ++jx)
            acc[i][jx] = (f32x4){0.f, 0.f, 0.f, 0.f};

    #pragma unroll 1
    for (int kt = 0; kt < DFEA / 32; ++kt) {
        const int k0 = kt * 32;
        bf16x8 va0 = load8_cvt(gA0 + k0);
        bf16x8 va1 = load8_cvt(gA1 + k0);
        bf16x8 vb0 = load8_cvt(gB0 + k0);
        bf16x8 vb1 = load8_cvt(gB1 + k0);
        __syncthreads();
        *(bf16x8*)&As[li0 * 8] = va0;
        *(bf16x8*)&As[li1 * 8] = va1;
        *(bf16x8*)&Bs[li0 * 8] = vb0;
        *(bf16x8*)&Bs[li1 * 8] = vb1;
        __syncthreads();

        bf16x8 af[4], bfr[4];
        #pragma unroll
        for (int i = 0; i < 4; ++i)
            af[i] = *(const bf16x8*)&As[(wmv * 64 + i * 16 + row16) * 32 + quad * 8];
        #pragma unroll
        for (int i = 0; i < 4; ++i)
            bfr[i] = *(const bf16x8*)&Bs[(wn * 64 + i * 16 + row16) * 32 + quad * 8];
        #pragma unroll
        for (int ai = 0; ai < 4; ++ai)
            #pragma unroll
            for (int bi = 0; bi < 4; ++bi)
                acc[ai][bi] = __builtin_amdgcn_mfma_f32_16x16x32_bf16(
                    af[ai], bfr[bi], acc[ai][bi], 0, 0, 0);
    }

    float s[4], cc[4], w2v[4];
    #pragma unroll
    for (int bi = 0; bi < 4; ++bi) {
        const int n = n0 + wn * 64 + bi * 16 + row16;
        const float sv = gmm[n] * rsqrtf(rvar[n] + EPS_BN);
        s[bi] = sv;
        cc[bi] = bta[n] + (b1[n] - rmean[n]) * sv;
        w2v[bi] = W2[n];
    }
    float p[4][4];
    #pragma unroll
    for (int ai = 0; ai < 4; ++ai)
        #pragma unroll
        for (int r = 0; r < 4; ++r) {
            float a = 0.f;
            #pragma unroll
            for (int bi = 0; bi < 4; ++bi) {
                float y = acc[ai][bi][r] * s[bi] + cc[bi];
                y = (y >= 0.f) ? y : SLOPE * y;
                a += y * w2v[bi];
            }
            p[ai][r] = a;
        }
    #pragma unroll
    for (int mask = 1; mask <= 8; mask <<= 1)
        #pragma unroll
        for (int ai = 0; ai < 4; ++ai)
            #pragma unroll
            for (int r = 0; r < 4; ++r)
                p[ai][r] += __shfl_xor(p[ai][r], mask);
    if (row16 == 0) {
        #pragma unroll
        for (int ai = 0; ai < 4; ++ai)
            #pragma unroll
            for (int r = 0; r < 4; ++r)
                red[wn][wmv * 64 + ai * 16 + quad * 4 + r] = p[ai][r];
    }
    __syncthreads();
    if (tid < 128)
        out[(size_t)(m0 + tid) * THEADS + t] = red[0][tid] + red[1][tid] + b2[t];
}

extern "C" void kernel_launch(void* const* d_in, const int* in_sizes, int n_in,
                              void* d_out, int out_size, void* d_ws, size_t ws_size,
                              hipStream_t stream) {
    (void)in_sizes; (void)n_in; (void)out_size;
    const float* f     = (const float*)d_in[0];
    const float* W1    = (const float*)d_in[1];
    const float* b1    = (const float*)d_in[2];
    const float* gmm   = (const float*)d_in[3];
    const float* bta   = (const float*)d_in[4];
    const float* rmean = (const float*)d_in[5];
    const float* rvar  = (const float*)d_in[6];
    const float* W2    = (const float*)d_in[7];
    const float* b2    = (const float*)d_in[8];
    float* out = (float*)d_out;

    if (ws_size >= WS_NEED) {
        __hip_bfloat16* fb  = (__hip_bfloat16*)d_ws;
        __hip_bfloat16* W1b = fb + N_F;
        cvt_pass<<<(C_T8 + 255) / 256, 256, 0, stream>>>(f, W1, fb);
        fused_heads_v3<<<dim3(NBLK3), 1024, 0, stream>>>(fb, W1b, b1, gmm, bta, rmean, rvar, W2, b2, out);
    } else {
        dim3 grid(BATCH / 128, THEADS);
        fused_heads_f32<<<grid, 256, 0, stream>>>(f, W1, b1, gmm, bta, rmean, rvar, W2, b2, out);
    }
}

// Round 3
// 384.442 us; speedup vs baseline: 4.0893x; 4.0893x over previous
//
#include <hip/hip_runtime.h>
#include <hip/hip_bf16.h>

// Problem constants
constexpr int BATCH = 8192;   // M
constexpr int THEADS = 137;   // number of predict heads
constexpr int DFEA = 384;     // reduction dim of GEMM1
constexpr int KHID = 128;     // per-head hidden width
constexpr float EPS_BN = 1e-5f;
constexpr float SLOPE = 0.01f;

constexpr size_t N_F  = (size_t)BATCH * DFEA;          // 3,145,728
constexpr size_t N_W1 = (size_t)THEADS * KHID * DFEA;  // 6,733,824
constexpr size_t WS_NEED = (N_F + N_W1) * sizeof(__hip_bfloat16);
constexpr int C_F8 = (int)(N_F / 8);                   // 393,216
constexpr int C_T8 = (int)((N_F + N_W1) / 8);          // 1,234,944

constexpr int GRP   = 8;                               // M-groups per head
constexpr int MB    = BATCH / GRP;                     // 1024 rows per block
constexpr int NBLK3 = THEADS * GRP;                    // 1096 blocks

typedef __attribute__((ext_vector_type(8))) short bf16x8;   // 8 bf16 = 4 VGPRs
typedef __attribute__((ext_vector_type(4))) float f32x4;

__device__ __forceinline__ short cvt_bf16(float x) {
    __hip_bfloat16 b = __float2bfloat16(x);
    return *(short*)&b;
}

__device__ __forceinline__ bf16x8 load8_cvt(const float* __restrict__ g) {
    f32x4 lo = *(const f32x4*)g;
    f32x4 hi = *(const f32x4*)(g + 4);
    bf16x8 r;
    r[0] = cvt_bf16(lo[0]); r[1] = cvt_bf16(lo[1]);
    r[2] = cvt_bf16(lo[2]); r[3] = cvt_bf16(lo[3]);
    r[4] = cvt_bf16(hi[0]); r[5] = cvt_bf16(hi[1]);
    r[6] = cvt_bf16(hi[2]); r[7] = cvt_bf16(hi[3]);
    return r;
}

__device__ __forceinline__ void gload16(const void* g, void* s) {
    // async global->LDS, 16B/lane; HW dest = readfirstlane(base) + lane*16
    __builtin_amdgcn_global_load_lds((const __attribute__((address_space(1))) void*)g,
                                     (__attribute__((address_space(3))) void*)s,
                                     16, 0, 0);
}

// ---------------- pre-pass: fp32 -> bf16 bulk convert (f then W1, one launch) ----
__global__ __launch_bounds__(256) void cvt_pass(const float* __restrict__ f,
                                                const float* __restrict__ W1,
                                                __hip_bfloat16* __restrict__ ws) {
    int i = blockIdx.x * 256 + threadIdx.x;
    if (i < C_F8)
        *(bf16x8*)(ws + (size_t)i * 8) = load8_cvt(f + (size_t)i * 8);
    else if (i < C_T8)
        *(bf16x8*)(ws + (size_t)i * 8) = load8_cvt(W1 + ((size_t)i - C_F8) * 8);
}

// 8 B-fragment ds_reads + 8 MFMA for one 16-row A-frag against the full 128-col panel,
// split 4+4 to cap live bfr registers at 16 (v3's 32-live bfr pushed allocation over).
// B LDS layout: [128 rows][24 slots of 16B]; slot (r,s) holds kblock (s&~7)|((s&7)^(r&7)).
__device__ __forceinline__ void mfma8(const bf16x8 af,
                                      const __hip_bfloat16* __restrict__ bsrc,
                                      int slotOff, int row16, f32x4 acc[8]) {
    bf16x8 bfr[4];
    #pragma unroll
    for (int bi = 0; bi < 4; ++bi)
        bfr[bi] = *(const bf16x8*)&bsrc[(size_t)((bi * 16 + row16) * 24 + slotOff) * 8];
    __builtin_amdgcn_s_setprio(1);
    #pragma unroll
    for (int bi = 0; bi < 4; ++bi)
        acc[bi] = __builtin_amdgcn_mfma_f32_16x16x32_bf16(af, bfr[bi], acc[bi], 0, 0, 0);
    __builtin_amdgcn_s_setprio(0);
    #pragma unroll
    for (int bi = 0; bi < 4; ++bi)
        bfr[bi] = *(const bf16x8*)&bsrc[(size_t)(((bi + 4) * 16 + row16) * 24 + slotOff) * 8];
    __builtin_amdgcn_s_setprio(1);
    #pragma unroll
    for (int bi = 0; bi < 4; ++bi)
        acc[bi + 4] = __builtin_amdgcn_mfma_f32_16x16x32_bf16(af, bfr[bi], acc[bi + 4], 0, 0, 0);
    __builtin_amdgcn_s_setprio(0);
}

// fused epilogue for one 16-row subtile: BN(eval) + LeakyReLU + dot(W2), in-wave reduce
__device__ __forceinline__ void epilogue_store(const f32x4 acc[8],
                                               const float* __restrict__ sc,
                                               const float* __restrict__ cc,
                                               const float* __restrict__ w2v,
                                               float b2t, int baseRow, int quad,
                                               int row16, int t, float* __restrict__ out) {
    float p[4];
    #pragma unroll
    for (int r = 0; r < 4; ++r) {
        float a = 0.f;
        #pragma unroll
        for (int bi = 0; bi < 8; ++bi) {
            float y = acc[bi][r] * sc[bi] + cc[bi];
            y = (y >= 0.f) ? y : SLOPE * y;   // LeakyReLU
            a += y * w2v[bi];
        }
        p[r] = a;
    }
    // reduce across 16 column-lanes (C/D col = lane&15); masks<16 stay in 16-lane group
    #pragma unroll
    for (int mask = 1; mask <= 8; mask <<= 1)
        #pragma unroll
        for (int r = 0; r < 4; ++r)
            p[r] += __shfl_xor(p[r], mask);
    if (row16 == 0) {
        #pragma unroll
        for (int r = 0; r < 4; ++r) {
            const int row = baseRow + quad * 4 + r;
            out[(size_t)row * THEADS + t] = p[r] + b2t;
        }
    }
}

// ---------------- main fused kernel v4: v3 structure, compilation contract fixed ----
// v3's algorithm was correct but the allocator targeted 8 waves/EU (VGPR=64) and
// spilled ~50 regs -> 4.2GB scratch traffic. Fix: pin waves/EU to exactly 4
// (VGPR budget 128, live set ~105 fits), split mfma8 4+4, and make the staged-half
// vmcnt(3) accounting exact with a sched_barrier after the epilogue-constant loads.
__global__ __launch_bounds__(1024)
__attribute__((amdgpu_waves_per_eu(4, 4)))
void fused_heads_v4(
    const __hip_bfloat16* __restrict__ fb,     // [8192, 384] bf16
    const __hip_bfloat16* __restrict__ W1b,    // [137*128, 384] bf16
    const float* __restrict__ b1,
    const float* __restrict__ gmm,
    const float* __restrict__ bta,
    const float* __restrict__ rmean,
    const float* __restrict__ rvar,
    const float* __restrict__ W2,
    const float* __restrict__ b2,
    float* __restrict__ out)                   // [8192, 137]
{
    __shared__ __attribute__((aligned(16))) __hip_bfloat16 Bs0[128 * 192]; // K   0..191, 48KB
    __shared__ __attribute__((aligned(16))) __hip_bfloat16 Bs1[128 * 192]; // K 192..383, 48KB

    const int tid   = threadIdx.x;
    const int lane  = tid & 63;
    const int w     = tid >> 6;          // wave 0..15, owns rows w*64..+64
    const int row16 = lane & 15;
    const int quad  = lane >> 4;
    const int xl    = row16 & 7;

    const int bid = blockIdx.x;
    const int t   = bid >> 3;            // head   (GRP == 8)
    const int mg  = bid & 7;             // m-group == XCD under round-robin dispatch
    const int m0  = mg * MB;
    const int n0  = t * KHID;

    // ---- epilogue constants (consumed before staging; sched_barrier pins order) ----
    float sc[8], cc[8], w2v[8];
    #pragma unroll
    for (int bi = 0; bi < 8; ++bi) {
        const int n = n0 + bi * 16 + row16;
        const float sv = gmm[n] * rsqrtf(rvar[n] + EPS_BN);
        sc[bi]  = sv;
        cc[bi]  = bta[n] + (b1[n] - rmean[n]) * sv;
        w2v[bi] = W2[n];
    }
    const float b2t = b2[t];
    __builtin_amdgcn_sched_barrier(0);   // no vmem from above drifts below this point

    // ---- stage B: half0 (3 gloads/thread) then half1 (3 gloads/thread) -----------
    #pragma unroll
    for (int h = 0; h < 2; ++h)
        #pragma unroll
        for (int i = 0; i < 3; ++i) {
            const int li = tid + i * 1024;           // 16B slot 0..3071 within half
            const int r  = li / 24;                  // B row 0..127
            const int s  = li - r * 24;              // slot-in-row 0..23
            const int kb = h * 24 + ((s & ~7) | ((s & 7) ^ (r & 7)));
            gload16(W1b + (size_t)(n0 + r) * DFEA + kb * 8,
                    (h ? Bs1 : Bs0) + (size_t)li * 8);
        }

    asm volatile("s_waitcnt vmcnt(3)" ::: "memory");  // oldest 3 = half0 complete
    __builtin_amdgcn_s_barrier();                     // half0 valid for all waves
    __builtin_amdgcn_sched_barrier(0);

    const __hip_bfloat16* aBase = fb + (size_t)(m0 + w * 64 + row16) * DFEA + quad * 8;
    const int q2e = quad ^ xl;          // even-kk bank-swizzled slot (low 3 bits)
    const int q2o = q2e ^ 4;            // odd-kk

    // ---- subtile 0 (peeled: mid-K barrier once half1 must be valid) --------------
    {
        f32x4 acc[8];
        #pragma unroll
        for (int bi = 0; bi < 8; ++bi) acc[bi] = (f32x4){0.f, 0.f, 0.f, 0.f};
        bf16x8 a0 = *(const bf16x8*)(aBase);
        bf16x8 a1 = *(const bf16x8*)(aBase + 32);
        #pragma unroll
        for (int ktl = 0; ktl < 12; ++ktl) {
            const bf16x8 af = a0;
            a0 = a1;
            if (ktl < 10) a1 = *(const bf16x8*)(aBase + (ktl + 2) * 32);
            const int kk = ktl % 6;
            mfma8(af, (ktl < 6) ? Bs0 : Bs1,
                  (kk >> 1) * 8 + ((kk & 1) ? q2o : q2e), row16, acc);
            if (ktl == 5) {
                asm volatile("s_waitcnt vmcnt(0)" ::: "memory"); // half1 staged
                __builtin_amdgcn_s_barrier();
                __builtin_amdgcn_sched_barrier(0);
            }
        }
        epilogue_store(acc, sc, cc, w2v, b2t, m0 + w * 64, quad, row16, t, out);
    }

    // ---- subtiles 1..3: fully barrier-free ---------------------------------------
    #pragma unroll 1
    for (int sub = 1; sub < 4; ++sub) {
        const __hip_bfloat16* aR = aBase + (size_t)sub * 16 * DFEA;
        f32x4 acc[8];
        #pragma unroll
        for (int bi = 0; bi < 8; ++bi) acc[bi] = (f32x4){0.f, 0.f, 0.f, 0.f};
        bf16x8 a0 = *(const bf16x8*)(aR);
        bf16x8 a1 = *(const bf16x8*)(aR + 32);
        #pragma unroll
        for (int ktl = 0; ktl < 12; ++ktl) {
            const bf16x8 af = a0;
            a0 = a1;
            if (ktl < 10) a1 = *(const bf16x8*)(aR + (ktl + 2) * 32);
            const int kk = ktl % 6;
            mfma8(af, (ktl < 6) ? Bs0 : Bs1,
                  (kk >> 1) * 8 + ((kk & 1) ? q2o : q2e), row16, acc);
        }
        epilogue_store(acc, sc, cc, w2v, b2t, m0 + w * 64 + sub * 16, quad, row16, t, out);
    }
}

// ---------------- fallback: direct fp32 path (unchanged) ---------------------------
__global__ __launch_bounds__(256) void fused_heads_f32(
    const float* __restrict__ f, const float* __restrict__ W1,
    const float* __restrict__ b1, const float* __restrict__ gmm,
    const float* __restrict__ bta, const float* __restrict__ rmean,
    const float* __restrict__ rvar, const float* __restrict__ W2,
    const float* __restrict__ b2, float* __restrict__ out)
{
    __shared__ __attribute__((aligned(16))) __hip_bfloat16 As[128 * 32];
    __shared__ __attribute__((aligned(16))) __hip_bfloat16 Bs[128 * 32];
    __shared__ float red[2][128];

    const int tid  = threadIdx.x;
    const int lane = tid & 63;
    const int wave = tid >> 6;
    const int wmv = wave >> 1, wn = wave & 1;
    const int m0 = blockIdx.x * 128;
    const int t  = blockIdx.y;
    const int n0 = t * KHID;

    const int li0 = tid, li1 = tid + 256;
    const int r0 = li0 >> 2, c0 = (li0 & 3) * 8;
    const int r1 = li1 >> 2, c1 = (li1 & 3) * 8;
    const float* gA0 = f  + (size_t)(m0 + r0) * DFEA + c0;
    const float* gA1 = f  + (size_t)(m0 + r1) * DFEA + c1;
    const float* gB0 = W1 + (size_t)(n0 + r0) * DFEA + c0;
    const float* gB1 = W1 + (size_t)(n0 + r1) * DFEA + c1;

    const int row16 = lane & 15, quad = lane >> 4;

    f32x4 acc[4][4];
    #pragma unroll
    for (int i = 0; i < 4; ++i)
        #pragma unroll
        for (int jx = 0; jx < 4; ++jx)
            acc[i][jx] = (f32x4){0.f, 0.f, 0.f, 0.f};

    #pragma unroll 1
    for (int kt = 0; kt < DFEA / 32; ++kt) {
        const int k0 = kt * 32;
        bf16x8 va0 = load8_cvt(gA0 + k0);
        bf16x8 va1 = load8_cvt(gA1 + k0);
        bf16x8 vb0 = load8_cvt(gB0 + k0);
        bf16x8 vb1 = load8_cvt(gB1 + k0);
        __syncthreads();
        *(bf16x8*)&As[li0 * 8] = va0;
        *(bf16x8*)&As[li1 * 8] = va1;
        *(bf16x8*)&Bs[li0 * 8] = vb0;
        *(bf16x8*)&Bs[li1 * 8] = vb1;
        __syncthreads();

        bf16x8 af[4], bfr[4];
        #pragma unroll
        for (int i = 0; i < 4; ++i)
            af[i] = *(const bf16x8*)&As[(wmv * 64 + i * 16 + row16) * 32 + quad * 8];
        #pragma unroll
        for (int i = 0; i < 4; ++i)
            bfr[i] = *(const bf16x8*)&Bs[(wn * 64 + i * 16 + row16) * 32 + quad * 8];
        #pragma unroll
        for (int ai = 0; ai < 4; ++ai)
            #pragma unroll
            for (int bi = 0; bi < 4; ++bi)
                acc[ai][bi] = __builtin_amdgcn_mfma_f32_16x16x32_bf16(
                    af[ai], bfr[bi], acc[ai][bi], 0, 0, 0);
    }

    float s[4], cc[4], w2v[4];
    #pragma unroll
    for (int bi = 0; bi < 4; ++bi) {
        const int n = n0 + wn * 64 + bi * 16 + row16;
        const float sv = gmm[n] * rsqrtf(rvar[n] + EPS_BN);
        s[bi] = sv;
        cc[bi] = bta[n] + (b1[n] - rmean[n]) * sv;
        w2v[bi] = W2[n];
    }
    float p[4][4];
    #pragma unroll
    for (int ai = 0; ai < 4; ++ai)
        #pragma unroll
        for (int r = 0; r < 4; ++r) {
            float a = 0.f;
            #pragma unroll
            for (int bi = 0; bi < 4; ++bi) {
                float y = acc[ai][bi][r] * s[bi] + cc[bi];
                y = (y >= 0.f) ? y : SLOPE * y;
                a += y * w2v[bi];
            }
            p[ai][r] = a;
        }
    #pragma unroll
    for (int mask = 1; mask <= 8; mask <<= 1)
        #pragma unroll
        for (int ai = 0; ai < 4; ++ai)
            #pragma unroll
            for (int r = 0; r < 4; ++r)
                p[ai][r] += __shfl_xor(p[ai][r], mask);
    if (row16 == 0) {
        #pragma unroll
        for (int ai = 0; ai < 4; ++ai)
            #pragma unroll
            for (int r = 0; r < 4; ++r)
                red[wn][wmv * 64 + ai * 16 + quad * 4 + r] = p[ai][r];
    }
    __syncthreads();
    if (tid < 128)
        out[(size_t)(m0 + tid) * THEADS + t] = red[0][tid] + red[1][tid] + b2[t];
}

extern "C" void kernel_launch(void* const* d_in, const int* in_sizes, int n_in,
                              void* d_out, int out_size, void* d_ws, size_t ws_size,
                              hipStream_t stream) {
    (void)in_sizes; (void)n_in; (void)out_size;
    const float* f     = (const float*)d_in[0];
    const float* W1    = (const float*)d_in[1];
    const float* b1    = (const float*)d_in[2];
    const float* gmm   = (const float*)d_in[3];
    const float* bta   = (const float*)d_in[4];
    const float* rmean = (const float*)d_in[5];
    const float* rvar  = (const float*)d_in[6];
    const float* W2    = (const float*)d_in[7];
    const float* b2    = (const float*)d_in[8];
    float* out = (float*)d_out;

    if (ws_size >= WS_NEED) {
        __hip_bfloat16* fb  = (__hip_bfloat16*)d_ws;
        __hip_bfloat16* W1b = fb + N_F;
        cvt_pass<<<(C_T8 + 255) / 256, 256, 0, stream>>>(f, W1, fb);
        fused_heads_v4<<<dim3(NBLK3), 1024, 0, stream>>>(fb, W1b, b1, gmm, bta, rmean, rvar, W2, b2, out);
    } else {
        dim3 grid(BATCH / 128, THEADS);
        fused_heads_f32<<<grid, 256, 0, stream>>>(f, W1, b1, gmm, bta, rmean, rvar, W2, b2, out);
    }
}

// Round 4
// 223.141 us; speedup vs baseline: 7.0453x; 1.7229x over previous
//
#include <hip/hip_runtime.h>
#include <hip/hip_bf16.h>

// Problem constants
constexpr int BATCH = 8192;   // M
constexpr int THEADS = 137;   // number of predict heads (grid.y)
constexpr int DFEA = 384;     // reduction dim of GEMM1
constexpr int KHID = 128;     // per-head hidden width
constexpr float EPS_BN = 1e-5f;
constexpr float SLOPE = 0.01f;

constexpr size_t N_F  = (size_t)BATCH * DFEA;          // 3,145,728
constexpr size_t N_W1 = (size_t)THEADS * KHID * DFEA;  // 6,733,824
constexpr size_t WS_NEED = (N_F + N_W1) * sizeof(__hip_bfloat16);
constexpr int C_F8 = (int)(N_F / 8);                   // 393,216
constexpr int C_T8 = (int)((N_F + N_W1) / 8);          // 1,234,944

typedef __attribute__((ext_vector_type(8))) short bf16x8;   // 8 bf16 = 4 VGPRs
typedef __attribute__((ext_vector_type(4))) float f32x4;

__device__ __forceinline__ short cvt_bf16(float x) {
    __hip_bfloat16 b = __float2bfloat16(x);
    return *(short*)&b;
}

__device__ __forceinline__ bf16x8 load8_cvt(const float* __restrict__ g) {
    f32x4 lo = *(const f32x4*)g;
    f32x4 hi = *(const f32x4*)(g + 4);
    bf16x8 r;
    r[0] = cvt_bf16(lo[0]); r[1] = cvt_bf16(lo[1]);
    r[2] = cvt_bf16(lo[2]); r[3] = cvt_bf16(lo[3]);
    r[4] = cvt_bf16(hi[0]); r[5] = cvt_bf16(hi[1]);
    r[6] = cvt_bf16(hi[2]); r[7] = cvt_bf16(hi[3]);
    return r;
}

__device__ __forceinline__ void gload16(const void* g, void* s) {
    // async global->LDS, 16B/lane; HW dest = readfirstlane(base) + lane*16
    __builtin_amdgcn_global_load_lds((const __attribute__((address_space(1))) void*)g,
                                     (__attribute__((address_space(3))) void*)s,
                                     16, 0, 0);
}

// ---------------- pre-pass: fp32 -> bf16 bulk convert (f then W1, one launch) ----
__global__ __launch_bounds__(256) void cvt_pass(const float* __restrict__ f,
                                                const float* __restrict__ W1,
                                                __hip_bfloat16* __restrict__ ws) {
    int i = blockIdx.x * 256 + threadIdx.x;
    if (i < C_F8)
        *(bf16x8*)(ws + (size_t)i * 8) = load8_cvt(f + (size_t)i * 8);
    else if (i < C_T8)
        *(bf16x8*)(ws + (size_t)i * 8) = load8_cvt(W1 + ((size_t)i - C_F8) * 8);
}

// ---------------- main fused kernel v5: v1 structure + 2-phase pipelined staging ----
// Identical tile/addressing to the verified v1 (256x128, 4 waves of 64x128, colblock
// swizzle cb ^ ((r>>1)&3), 0 bank conflicts), with ONE structural change (T3/T4):
// LDS tiles are double-buffered; tile k+1's global_load_lds batch is issued BEFORE
// computing tile k, and the pre-compute wait is a counted s_waitcnt vmcnt(6) (the 6
// in-flight loads are the NEXT tile's), so each tile's HBM/L2 latency hides under
// the previous tile's ds_read+MFMA instead of being serially exposed at a full
// vmcnt(0) drain (v1's __syncthreads). vmcnt accounting is exact: the K-loop issues
// no vmem other than the 6 stage loads (epilogue constants load after the loop).
__global__ __launch_bounds__(256, 2) void fused_heads_v5(
    const __hip_bfloat16* __restrict__ fb,     // [8192, 384] bf16
    const __hip_bfloat16* __restrict__ W1b,    // [137*128, 384] bf16
    const float* __restrict__ b1,
    const float* __restrict__ gmm,
    const float* __restrict__ bta,
    const float* __restrict__ rmean,
    const float* __restrict__ rvar,
    const float* __restrict__ W2,
    const float* __restrict__ b2,
    float* __restrict__ out)                   // [8192, 137]
{
    __shared__ __attribute__((aligned(16))) __hip_bfloat16 As[2][256 * 32];  // 2x16 KB
    __shared__ __attribute__((aligned(16))) __hip_bfloat16 Bs[2][128 * 32];  // 2x 8 KB

    const int tid  = threadIdx.x;
    const int lane = tid & 63;
    const int wm   = tid >> 6;          // wave = M-slice (0..3), rows wm*64..+64
    const int m0 = blockIdx.x * 256;
    const int t  = blockIdx.y;
    const int n0 = t * KHID;

    const int row16 = lane & 15;
    const int quad  = lane >> 4;
    const int swz   = quad ^ ((row16 >> 1) & 3);   // swizzled k-colblock for reads

    // staging sources: A chunks li = tid + c*256 (c=0..3), B chunks c=0..1
    // chunk li -> LDS bytes li*16; global row r=li>>2, colblock (li&3)^((li>>3)&3)
    const __hip_bfloat16* gA[4];
    const __hip_bfloat16* gB[2];
    #pragma unroll
    for (int c = 0; c < 4; ++c) {
        const int li = tid + c * 256;
        const int r = li >> 2, cb = (li & 3) ^ ((li >> 3) & 3);
        gA[c] = fb + (size_t)(m0 + r) * DFEA + cb * 8;
    }
    #pragma unroll
    for (int c = 0; c < 2; ++c) {
        const int li = tid + c * 256;
        const int r = li >> 2, cb = (li & 3) ^ ((li >> 3) & 3);
        gB[c] = W1b + (size_t)(n0 + r) * DFEA + cb * 8;
    }

    f32x4 acc[4][8];
    #pragma unroll
    for (int i = 0; i < 4; ++i)
        #pragma unroll
        for (int j = 0; j < 8; ++j)
            acc[i][j] = (f32x4){0.f, 0.f, 0.f, 0.f};

#define STAGE(BUF, K0)                                                      \
    {                                                                       \
        _Pragma("unroll")                                                   \
        for (int c = 0; c < 4; ++c)                                         \
            gload16(gA[c] + (K0), &As[BUF][(tid + c * 256) * 8]);           \
        _Pragma("unroll")                                                   \
        for (int c = 0; c < 2; ++c)                                         \
            gload16(gB[c] + (K0), &Bs[BUF][(tid + c * 256) * 8]);           \
    }

    STAGE(0, 0);   // prologue: tile 0 -> buf 0 (6 loads in flight)

    #pragma unroll 2
    for (int kt = 0; kt < DFEA / 32; ++kt) {
        const int cur = kt & 1;
        // issue next tile's stage FIRST (into the buffer whose readers finished at
        // the end-of-iteration barrier of kt-1), then wait only for tile kt's loads
        if (kt < 11) {
            STAGE(cur ^ 1, (kt + 1) * 32);
            asm volatile("s_waitcnt vmcnt(6)" ::: "memory");  // 6 newest = tile kt+1
        } else {
            asm volatile("s_waitcnt vmcnt(0)" ::: "memory");
        }
        __builtin_amdgcn_s_barrier();         // tile kt valid for all waves
        __builtin_amdgcn_sched_barrier(0);

        bf16x8 af[4], bfr[8];
        #pragma unroll
        for (int ai = 0; ai < 4; ++ai)
            af[ai] = *(const bf16x8*)&As[cur][(wm * 64 + ai * 16 + row16) * 32 + swz * 8];
        #pragma unroll
        for (int bi = 0; bi < 8; ++bi)
            bfr[bi] = *(const bf16x8*)&Bs[cur][(bi * 16 + row16) * 32 + swz * 8];

        __builtin_amdgcn_s_setprio(1);
        #pragma unroll
        for (int ai = 0; ai < 4; ++ai)
            #pragma unroll
            for (int bi = 0; bi < 8; ++bi)
                acc[ai][bi] = __builtin_amdgcn_mfma_f32_16x16x32_bf16(
                    af[ai], bfr[bi], acc[ai][bi], 0, 0, 0);
        __builtin_amdgcn_s_setprio(0);

        __builtin_amdgcn_s_barrier();         // all reads of buf[cur] done ->
                                              // safe to overwrite at iter kt+1
    }
#undef STAGE

    // ---- fused epilogue: BN (eval) + LeakyReLU + dot with W2, all in-wave ----
    float s[8], cc[8], w2v[8];
    #pragma unroll
    for (int bi = 0; bi < 8; ++bi) {
        const int n = n0 + bi * 16 + row16;
        const float sv = gmm[n] * rsqrtf(rvar[n] + EPS_BN);
        s[bi]   = sv;
        cc[bi]  = bta[n] + (b1[n] - rmean[n]) * sv;
        w2v[bi] = W2[n];
    }

    float p[4][4];
    #pragma unroll
    for (int ai = 0; ai < 4; ++ai)
        #pragma unroll
        for (int r = 0; r < 4; ++r) {
            float a = 0.f;
            #pragma unroll
            for (int bi = 0; bi < 8; ++bi) {
                float y = acc[ai][bi][r] * s[bi] + cc[bi];
                y = (y >= 0.f) ? y : SLOPE * y;   // LeakyReLU
                a += y * w2v[bi];
            }
            p[ai][r] = a;
        }

    // reduce across the 16 column-lanes (C/D: col = lane&15); masks<16 stay in-quad
    #pragma unroll
    for (int mask = 1; mask <= 8; mask <<= 1)
        #pragma unroll
        for (int ai = 0; ai < 4; ++ai)
            #pragma unroll
            for (int r = 0; r < 4; ++r)
                p[ai][r] += __shfl_xor(p[ai][r], mask);

    if (row16 == 0) {
        const float bias = b2[t];
        #pragma unroll
        for (int ai = 0; ai < 4; ++ai)
            #pragma unroll
            for (int r = 0; r < 4; ++r) {
                const int row = m0 + wm * 64 + ai * 16 + quad * 4 + r;
                out[(size_t)row * THEADS + t] = p[ai][r] + bias;
            }
    }
}

// ---------------- fallback: direct fp32 path (unchanged) ---------------------------
__global__ __launch_bounds__(256) void fused_heads_f32(
    const float* __restrict__ f, const float* __restrict__ W1,
    const float* __restrict__ b1, const float* __restrict__ gmm,
    const float* __restrict__ bta, const float* __restrict__ rmean,
    const float* __restrict__ rvar, const float* __restrict__ W2,
    const float* __restrict__ b2, float* __restrict__ out)
{
    __shared__ __attribute__((aligned(16))) __hip_bfloat16 As[128 * 32];
    __shared__ __attribute__((aligned(16))) __hip_bfloat16 Bs[128 * 32];
    __shared__ float red[2][128];

    const int tid  = threadIdx.x;
    const int lane = tid & 63;
    const int wave = tid >> 6;
    const int wmv = wave >> 1, wn = wave & 1;
    const int m0 = blockIdx.x * 128;
    const int t  = blockIdx.y;
    const int n0 = t * KHID;

    const int li0 = tid, li1 = tid + 256;
    const int r0 = li0 >> 2, c0 = (li0 & 3) * 8;
    const int r1 = li1 >> 2, c1 = (li1 & 3) * 8;
    const float* gA0 = f  + (size_t)(m0 + r0) * DFEA + c0;
    const float* gA1 = f  + (size_t)(m0 + r1) * DFEA + c1;
    const float* gB0 = W1 + (size_t)(n0 + r0) * DFEA + c0;
    const float* gB1 = W1 + (size_t)(n0 + r1) * DFEA + c1;

    const int row16 = lane & 15, quad = lane >> 4;

    f32x4 acc[4][4];
    #pragma unroll
    for (int i = 0; i < 4; ++i)
        #pragma unroll
        for (int jx = 0; jx < 4; ++jx)
            acc[i][jx] = (f32x4){0.f, 0.f, 0.f, 0.f};

    #pragma unroll 1
    for (int kt = 0; kt < DFEA / 32; ++kt) {
        const int k0 = kt * 32;
        bf16x8 va0 = load8_cvt(gA0 + k0);
        bf16x8 va1 = load8_cvt(gA1 + k0);
        bf16x8 vb0 = load8_cvt(gB0 + k0);
        bf16x8 vb1 = load8_cvt(gB1 + k0);
        __syncthreads();
        *(bf16x8*)&As[li0 * 8] = va0;
        *(bf16x8*)&As[li1 * 8] = va1;
        *(bf16x8*)&Bs[li0 * 8] = vb0;
        *(bf16x8*)&Bs[li1 * 8] = vb1;
        __syncthreads();

        bf16x8 af[4], bfr[4];
        #pragma unroll
        for (int i = 0; i < 4; ++i)
            af[i] = *(const bf16x8*)&As[(wmv * 64 + i * 16 + row16) * 32 + quad * 8];
        #pragma unroll
        for (int i = 0; i < 4; ++i)
            bfr[i] = *(const bf16x8*)&Bs[(wn * 64 + i * 16 + row16) * 32 + quad * 8];
        #pragma unroll
        for (int ai = 0; ai < 4; ++ai)
            #pragma unroll
            for (int bi = 0; bi < 4; ++bi)
                acc[ai][bi] = __builtin_amdgcn_mfma_f32_16x16x32_bf16(
                    af[ai], bfr[bi], acc[ai][bi], 0, 0, 0);
    }

    float s[4], cc[4], w2v[4];
    #pragma unroll
    for (int bi = 0; bi < 4; ++bi) {
        const int n = n0 + wn * 64 + bi * 16 + row16;
        const float sv = gmm[n] * rsqrtf(rvar[n] + EPS_BN);
        s[bi] = sv;
        cc[bi] = bta[n] + (b1[n] - rmean[n]) * sv;
        w2v[bi] = W2[n];
    }
    float p[4][4];
    #pragma unroll
    for (int ai = 0; ai < 4; ++ai)
        #pragma unroll
        for (int r = 0; r < 4; ++r) {
            float a = 0.f;
            #pragma unroll
            for (int bi = 0; bi < 4; ++bi) {
                float y = acc[ai][bi][r] * s[bi] + cc[bi];
                y = (y >= 0.f) ? y : SLOPE * y;
                a += y * w2v[bi];
            }
            p[ai][r] = a;
        }
    #pragma unroll
    for (int mask = 1; mask <= 8; mask <<= 1)
        #pragma unroll
        for (int ai = 0; ai < 4; ++ai)
            #pragma unroll
            for (int r = 0; r < 4; ++r)
                p[ai][r] += __shfl_xor(p[ai][r], mask);
    if (row16 == 0) {
        #pragma unroll
        for (int ai = 0; ai < 4; ++ai)
            #pragma unroll
            for (int r = 0; r < 4; ++r)
                red[wn][wmv * 64 + ai * 16 + quad * 4 + r] = p[ai][r];
    }
    __syncthreads();
    if (tid < 128)
        out[(size_t)(m0 + tid) * THEADS + t] = red[0][tid] + red[1][tid] + b2[t];
}

extern "C" void kernel_launch(void* const* d_in, const int* in_sizes, int n_in,
                              void* d_out, int out_size, void* d_ws, size_t ws_size,
                              hipStream_t stream) {
    (void)in_sizes; (void)n_in; (void)out_size;
    const float* f     = (const float*)d_in[0];
    const float* W1    = (const float*)d_in[1];
    const float* b1    = (const float*)d_in[2];
    const float* gmm   = (const float*)d_in[3];
    const float* bta   = (const float*)d_in[4];
    const float* rmean = (const float*)d_in[5];
    const float* rvar  = (const float*)d_in[6];
    const float* W2    = (const float*)d_in[7];
    const float* b2    = (const float*)d_in[8];
    float* out = (float*)d_out;

    if (ws_size >= WS_NEED) {
        __hip_bfloat16* fb  = (__hip_bfloat16*)d_ws;
        __hip_bfloat16* W1b = fb + N_F;
        cvt_pass<<<(C_T8 + 255) / 256, 256, 0, stream>>>(f, W1, fb);
        dim3 grid(BATCH / 256, THEADS);
        fused_heads_v5<<<grid, 256, 0, stream>>>(fb, W1b, b1, gmm, bta, rmean, rvar, W2, b2, out);
    } else {
        dim3 grid(BATCH / 128, THEADS);
        fused_heads_f32<<<grid, 256, 0, stream>>>(f, W1, b1, gmm, bta, rmean, rvar, W2, b2, out);
    }
}